// Round 17
// baseline (187.513 us; speedup 1.0000x reference)
//
#include <hip/hip_runtime.h>
#include <hip/hip_bf16.h>

typedef __bf16 bf16;
typedef __bf16 bf16x4 __attribute__((ext_vector_type(4)));
typedef __bf16 bf16x8 __attribute__((ext_vector_type(8)));
typedef float f32x4 __attribute__((ext_vector_type(4)));

#define MFMA16(a, b, c) __builtin_amdgcn_mfma_f32_16x16x32_bf16((a), (b), (c), 0, 0, 0)

// async global->LDS, 16B per lane; LDS dest = wave-uniform base + lane*16.
__device__ __forceinline__ void async16(const void* g, void* l) {
  typedef const unsigned int __attribute__((address_space(1))) * GP;
  typedef unsigned int __attribute__((address_space(3))) * LP;
  __builtin_amdgcn_global_load_lds((GP)g, (LP)l, 16, 0, 0);
}

// ---------------------------------------------------------------------------
// prep: z<4 -> transpose+convert weight z (fp32 [1024x1024] -> bf16 Wt[n][k]);
// z==4 -> convert x fp32 -> bf16; z==5 -> zero d_out (proj accumulates into
// it with atomics; harness re-poisons it before every timed replay).
// grid (16,16,6) x 256 threads.
// ---------------------------------------------------------------------------
__global__ __launch_bounds__(256) void prep(
    const float* __restrict__ w0, const float* __restrict__ w1,
    const float* __restrict__ w2, const float* __restrict__ w3,
    const float* __restrict__ x, bf16* __restrict__ wtOut,
    bf16* __restrict__ xOut, float* __restrict__ outZero) {
  const int t = threadIdx.x;
  if (blockIdx.z == 5) {  // zero d_out: 4M floats over 256 blocks
    size_t base = ((size_t)(blockIdx.y * 16 + blockIdx.x)) * 16384;
#pragma unroll
    for (int p = 0; p < 16; ++p) {
      size_t i = base + (size_t)(p * 256 + t) * 4;
      *(f32x4*)&outZero[i] = (f32x4){0.f, 0.f, 0.f, 0.f};
    }
    return;
  }
  if (blockIdx.z == 4) {  // x conversion
    size_t base = ((size_t)(blockIdx.y * 16 + blockIdx.x)) * 16384;
#pragma unroll
    for (int p = 0; p < 16; ++p) {
      size_t i = base + (size_t)(p * 256 + t) * 4;
      f32x4 v = *(const f32x4*)&x[i];
      bf16 o[4];
#pragma unroll
      for (int j = 0; j < 4; ++j) o[j] = (bf16)v[j];
      *(ulong1*)&xOut[i] = *(ulong1*)o;
    }
    return;
  }
  __shared__ __align__(16) float tile[64][68];
  const float* src = (blockIdx.z == 0) ? w0 : (blockIdx.z == 1) ? w1
                   : (blockIdx.z == 2) ? w2 : w3;
  bf16* dst = wtOut + (size_t)blockIdx.z * (1024u * 1024u);
  const int bx = blockIdx.x, by = blockIdx.y;
#pragma unroll
  for (int p = 0; p < 4; ++p) {
    int idx = t + p * 256;
    int r = idx >> 4, c4 = idx & 15;
    *(f32x4*)&tile[r][c4 * 4] =
        *(const f32x4*)&src[(size_t)(by * 64 + r) * 1024 + bx * 64 + c4 * 4];
  }
  __syncthreads();
#pragma unroll
  for (int p = 0; p < 2; ++p) {
    int idx = t + p * 256;
    int rn = idx >> 3, c8 = idx & 7;
    bf16x8 v;
#pragma unroll
    for (int i = 0; i < 8; ++i) v[i] = (bf16)tile[c8 * 8 + i][rn];
    *(bf16x8*)&dst[(size_t)(bx * 64 + rn) * 1024 + by * 64 + c8 * 8] = v;
  }
}

// ---------------------------------------------------------------------------
// QKV GEMM (round-13): C = A @ W (Bt[n][k]). 128 x (NI*32) tile, BK=32 dbuf
// global_load_lds, one barrier per K-step. XCD-swizzled 1D grid:
// bid = (y&7) + 8*(x + XT*(y>>3)); z in grid.y.
// z==0 scaled by scaleZ0; z==2: fused V^T epilogue with PI-PERMUTED keys
// (key s=16h+4q+r stored at col 8q+4h+r within each 32-block) so attention's
// PV B-frag is ONE contiguous b128.
// ---------------------------------------------------------------------------
template <typename OutT, int NI>
__global__ __launch_bounds__(256, 4) void gemm_bt(
    const bf16* __restrict__ A, const bf16* __restrict__ Bt,
    OutT* __restrict__ C, int btStrideZ, int cStrideZ, float scaleZ0,
    bf16* __restrict__ vtOut) {
  constexpr int XT = 1024 / (NI * 32);
  const int bid = blockIdx.x;
  const int rr = bid & 7, tt = bid >> 3;
  const int xb = tt % XT, yb = (tt / XT) * 8 + rr;
  const int zi = blockIdx.y;

  const int tid = threadIdx.x;
  const int wave = tid >> 6, lane = tid & 63;
  const int quad = lane >> 4, l16 = lane & 15;
  const int wm = wave >> 1, wn = wave & 1;
  const int m0 = yb * 128, n0 = xb * (NI * 32);
  const bf16* Bz = Bt + (size_t)zi * (size_t)btStrideZ;
  OutT* Cz = C + (size_t)zi * (size_t)cStrideZ;
  const float sc = (zi == 0) ? scaleZ0 : 1.0f;

  __shared__ __align__(16) bf16 lsA[2][128 * 32];
  __shared__ __align__(16) bf16 lsB[2][NI * 32 * 32];

  const int lrow = lane >> 2;
  const int cgX = (lane & 3) ^ ((lrow >> 1) & 3);
  const int fR = (l16 >> 1) & 3;

  f32x4 acc[4][NI];
#pragma unroll
  for (int i = 0; i < 4; ++i)
#pragma unroll
    for (int j = 0; j < NI; ++j) acc[i][j] = (f32x4){0.f, 0.f, 0.f, 0.f};

#pragma unroll
  for (int c = 0; c < 2; ++c) {
    int chunk = wave * 2 + c;
    int row = chunk * 16 + lrow;
    async16(&A[(size_t)(m0 + row) * 1024 + cgX * 8], &lsA[0][chunk * 512]);
  }
#pragma unroll
  for (int c = 0; c < NI / 2; ++c) {
    int chunk = wave * (NI / 2) + c;
    int row = chunk * 16 + lrow;
    async16(&Bz[(size_t)(n0 + row) * 1024 + cgX * 8], &lsB[0][chunk * 512]);
  }
  __syncthreads();

  for (int it = 0; it < 32; ++it) {
    const int cur = it & 1;
    if (it < 31) {
      int k0n = (it + 1) * 32;
#pragma unroll
      for (int c = 0; c < 2; ++c) {
        int chunk = wave * 2 + c;
        int row = chunk * 16 + lrow;
        async16(&A[(size_t)(m0 + row) * 1024 + k0n + cgX * 8],
                &lsA[cur ^ 1][chunk * 512]);
      }
#pragma unroll
      for (int c = 0; c < NI / 2; ++c) {
        int chunk = wave * (NI / 2) + c;
        int row = chunk * 16 + lrow;
        async16(&Bz[(size_t)(n0 + row) * 1024 + k0n + cgX * 8],
                &lsB[cur ^ 1][chunk * 512]);
      }
    }

    bf16x8 af[4], bfr[NI];
#pragma unroll
    for (int i = 0; i < 4; ++i) {
      int ra = wm * 64 + i * 16 + l16;
      af[i] = *(const bf16x8*)&lsA[cur][ra * 32 + ((quad ^ fR) * 8)];
    }
#pragma unroll
    for (int ni = 0; ni < NI; ++ni) {
      int rb = wn * (NI * 16) + ni * 16 + l16;
      bfr[ni] = *(const bf16x8*)&lsB[cur][rb * 32 + ((quad ^ fR) * 8)];
    }
#pragma unroll
    for (int mi = 0; mi < 4; ++mi)
#pragma unroll
      for (int ni = 0; ni < NI; ++ni)
        acc[mi][ni] = MFMA16(af[mi], bfr[ni], acc[mi][ni]);

    __syncthreads();
  }

  if (zi == 2 && vtOut != nullptr) {
    // V: transposed per head -> vt[(b*16+h)][d][sPerm], pi-permuted keys.
#pragma unroll
    for (int mi = 0; mi < 4; ++mi)
#pragma unroll
      for (int ni = 0; ni < NI; ++ni) {
        int col = n0 + wn * (NI * 16) + ni * 16 + l16;
        int hd = col >> 6, d = col & 63;
        int row = m0 + wm * 64 + mi * 16 + quad * 4;
        int b = row >> 11, s = row & 2047;
        int s32 = s & 31;
        int sp = (s & ~31) + ((s32 & 12) << 1) + ((s32 >> 4) << 2);
        bf16 o[4];
#pragma unroll
        for (int r = 0; r < 4; ++r) o[r] = (bf16)acc[mi][ni][r];
        *(ulong1*)&vtOut[((size_t)(b * 16 + hd) * 64 + d) * 2048 + sp] =
            *(ulong1*)o;
      }
  } else {
#pragma unroll
    for (int mi = 0; mi < 4; ++mi)
#pragma unroll
      for (int ni = 0; ni < NI; ++ni) {
        int col = n0 + wn * (NI * 16) + ni * 16 + l16;
#pragma unroll
        for (int r = 0; r < 4; ++r) {
          int row = m0 + wm * 64 + mi * 16 + quad * 4 + r;
          Cz[(size_t)row * 1024 + col] = (OutT)(acc[mi][ni][r] * sc);
        }
      }
  }
}

// ---------------------------------------------------------------------------
// Output projection, SPLIT-K=2 with fp32 atomicAdd epilogue. 128x64 tile,
// K-half = 512 (16 BK=32 steps, dbuf, one barrier/step). Grid 1024 ->
// 4 blocks/CU co-resident; per-block barrier count halves vs full-K.
// Decode: rr=bid&7 (XCD), y64=(tt/16)*8+rr -> kh=y64&1, yb=y64>>1: same-XCD
// blocks share the k-half AND A rows (per-XCD A+W footprint ~2MB, L2-hot).
// d_out is pre-zeroed by prep z==5; each output touched by exactly 2 blocks.
// ---------------------------------------------------------------------------
__global__ __launch_bounds__(256, 4) void gemm_proj_sk(
    const bf16* __restrict__ A, const bf16* __restrict__ Bt,
    float* __restrict__ C) {
  const int bid = blockIdx.x;
  const int rr = bid & 7, tt = bid >> 3;     // tt 0..127
  const int xb = tt % 16;
  const int y64 = (tt / 16) * 8 + rr;        // 0..63
  const int kh = y64 & 1, yb = y64 >> 1;     // k-half, y-tile 0..31
  const int k0b = kh * 512;

  const int tid = threadIdx.x;
  const int wave = tid >> 6, lane = tid & 63;
  const int quad = lane >> 4, l16 = lane & 15;
  const int wm = wave >> 1, wn = wave & 1;
  const int m0 = yb * 128, n0 = xb * 64;

  __shared__ __align__(16) bf16 lsA[2][128 * 32];  // 8KB per buf
  __shared__ __align__(16) bf16 lsB[2][64 * 32];   // 4KB per buf

  const int lrow = lane >> 2;
  const int cgX = (lane & 3) ^ ((lrow >> 1) & 3);
  const int fR = (l16 >> 1) & 3;

  f32x4 acc[4][2];
#pragma unroll
  for (int i = 0; i < 4; ++i)
#pragma unroll
    for (int j = 0; j < 2; ++j) acc[i][j] = (f32x4){0.f, 0.f, 0.f, 0.f};

#pragma unroll
  for (int c = 0; c < 2; ++c) {
    int chunk = wave * 2 + c;
    int row = chunk * 16 + lrow;
    async16(&A[(size_t)(m0 + row) * 1024 + k0b + cgX * 8],
            &lsA[0][chunk * 512]);
  }
  {
    int row = wave * 16 + lrow;  // 4 chunks of 16 rows (64 B rows)
    async16(&Bt[(size_t)(n0 + row) * 1024 + k0b + cgX * 8],
            &lsB[0][wave * 512]);
  }
  __syncthreads();

  for (int it = 0; it < 16; ++it) {
    const int cur = it & 1;
    if (it < 15) {
      int k0n = k0b + (it + 1) * 32;
#pragma unroll
      for (int c = 0; c < 2; ++c) {
        int chunk = wave * 2 + c;
        int row = chunk * 16 + lrow;
        async16(&A[(size_t)(m0 + row) * 1024 + k0n + cgX * 8],
                &lsA[cur ^ 1][chunk * 512]);
      }
      {
        int row = wave * 16 + lrow;
        async16(&Bt[(size_t)(n0 + row) * 1024 + k0n + cgX * 8],
                &lsB[cur ^ 1][wave * 512]);
      }
    }

    bf16x8 af[4], bfr[2];
#pragma unroll
    for (int i = 0; i < 4; ++i) {
      int ra = wm * 64 + i * 16 + l16;
      af[i] = *(const bf16x8*)&lsA[cur][ra * 32 + ((quad ^ fR) * 8)];
    }
#pragma unroll
    for (int ni = 0; ni < 2; ++ni) {
      int rb = wn * 32 + ni * 16 + l16;
      bfr[ni] = *(const bf16x8*)&lsB[cur][rb * 32 + ((quad ^ fR) * 8)];
    }
#pragma unroll
    for (int mi = 0; mi < 4; ++mi)
#pragma unroll
      for (int ni = 0; ni < 2; ++ni)
        acc[mi][ni] = MFMA16(af[mi], bfr[ni], acc[mi][ni]);

    __syncthreads();
  }

  // epilogue: accumulate into pre-zeroed d_out (2 contributors per element)
#pragma unroll
  for (int mi = 0; mi < 4; ++mi)
#pragma unroll
    for (int ni = 0; ni < 2; ++ni) {
      int col = n0 + wn * 32 + ni * 16 + l16;
#pragma unroll
      for (int r = 0; r < 4; ++r) {
        int row = m0 + wm * 64 + mi * 16 + quad * 4 + r;
        atomicAdd(&C[(size_t)row * 1024 + col], acc[mi][ni][r]);
      }
    }
}

// ---------------------------------------------------------------------------
// Flash attention v7 (round-16, kept: measured < 44 us): register-resident P
// + 4-slot LDS rotation, one barrier per PAIR of 64-key tiles. LDS 64KB,
// 512 thr, 128-row q-tile, 8 waves x 16 q-rows; pi-permuted V -> PV B-frag
// is one b128. Q pre-scaled by 0.125*log2e -> p = exp2(s).
// ---------------------------------------------------------------------------
__global__ __launch_bounds__(512, 4) void attn_fwd(
    const bf16* __restrict__ Q, const bf16* __restrict__ K,
    const bf16* __restrict__ Vt, bf16* __restrict__ O) {
  const int bid = blockIdx.x;
  const int x = bid & 15, hb = bid >> 4;
  const int h = hb & 15, b = hb >> 4;
  const int qt = b ? (15 - x) : x;
  const int tid = threadIdx.x;
  const int wave = tid >> 6, lane = tid & 63;
  const int quad = lane >> 4, l16 = lane & 15;

  __shared__ __align__(16) bf16 SMEM[32768];  // 64 KB, 4 slots x 8192
  bf16* Qs = &SMEM[16384];  // Q overlays slot 2

  const size_t base = ((size_t)b * 2048) * 1024 + (size_t)h * 64;
  const bf16* Qb = Q + base;
  const bf16* Kb = K + base;
  const bf16* Vtb = Vt + ((size_t)(b * 16 + h)) * 64 * 2048;
  bf16* Ob = O + base;

  const int lrow = lane >> 3;
  const int cgX = (lane & 7) ^ lrow;

#pragma unroll
  for (int c = 0; c < 2; ++c) {
    int chunk = wave * 2 + c;
    int row = chunk * 8 + lrow;
    async16(&Qb[(size_t)(qt * 128 + row) * 1024 + cgX * 8], &Qs[chunk * 512]);
  }
  {
    int row = wave * 8 + lrow;
    async16(&Kb[(size_t)row * 1024 + cgX * 8], &SMEM[0 * 8192 + wave * 512]);
    async16(&Vtb[(size_t)row * 2048 + cgX * 8],
            &SMEM[0 * 8192 + 4096 + wave * 512]);
    async16(&Kb[(size_t)(64 + row) * 1024 + cgX * 8],
            &SMEM[1 * 8192 + wave * 512]);
    async16(&Vtb[(size_t)row * 2048 + 64 + cgX * 8],
            &SMEM[1 * 8192 + 4096 + wave * 512]);
  }
  __syncthreads();

  bf16x8 aq[2];
#pragma unroll
  for (int ks = 0; ks < 2; ++ks) {
    int row = wave * 16 + l16;
    aq[ks] = *(const bf16x8*)&Qs[row * 64 + (((ks * 4 + quad) ^ (l16 & 7)) * 8)];
  }
  __syncthreads();  // Q-frag reads done before slot 2 is overwritten

  const float NEG_INF = -__builtin_inff();
  f32x4 lsv = (f32x4){0.f, 0.f, 0.f, 0.f};
  f32x4 Oacc[4];
#pragma unroll
  for (int nt = 0; nt < 4; ++nt) Oacc[nt] = (f32x4){0.f, 0.f, 0.f, 0.f};

  const int kt_end = 2 * qt + 1;           // tile count 2qt+2 (even)
  const int ktd = 2 * qt + (wave >> 2);    // this wave's diagonal tile

  for (int ktp = 0; ktp <= kt_end; ktp += 2) {
    {
      int row = wave * 8 + lrow;
      if (ktp + 2 <= kt_end) {
        int s2 = (ktp + 2) & 3;
        async16(&Kb[(size_t)((ktp + 2) * 64 + row) * 1024 + cgX * 8],
                &SMEM[s2 * 8192 + wave * 512]);
        async16(&Vtb[(size_t)row * 2048 + (ktp + 2) * 64 + cgX * 8],
                &SMEM[s2 * 8192 + 4096 + wave * 512]);
      }
      if (ktp + 3 <= kt_end) {
        int s3 = (ktp + 3) & 3;
        async16(&Kb[(size_t)((ktp + 3) * 64 + row) * 1024 + cgX * 8],
                &SMEM[s3 * 8192 + wave * 512]);
        async16(&Vtb[(size_t)row * 2048 + (ktp + 3) * 64 + cgX * 8],
                &SMEM[s3 * 8192 + 4096 + wave * 512]);
      }
    }

#pragma unroll
    for (int sub = 0; sub < 2; ++sub) {
      const int kt = ktp + sub;
      const int ko = (kt & 3) * 8192;
      const int vo = ko + 4096;
      if (kt <= ktd) {
        f32x4 sv[4];
#pragma unroll
        for (int nt = 0; nt < 4; ++nt) {
          int row = nt * 16 + l16;
          bf16x8 bk0 = *(const bf16x8*)&SMEM[ko + row * 64 +
                                             ((quad ^ (l16 & 7)) * 8)];
          bf16x8 bk1 = *(const bf16x8*)&SMEM[ko + row * 64 +
                                             (((4 + quad) ^ (l16 & 7)) * 8)];
          sv[nt] = (f32x4){0.f, 0.f, 0.f, 0.f};
          sv[nt] = MFMA16(bk0, aq[0], sv[nt]);
          sv[nt] = MFMA16(bk1, aq[1], sv[nt]);
        }

        if (kt == ktd) {
          const int q_rel = wave * 16 + l16;
          const int cb = (kt - 2 * qt) * 64;
#pragma unroll
          for (int nt = 0; nt < 4; ++nt) {
            const int kb = cb + nt * 16 + quad * 4;
#pragma unroll
            for (int r = 0; r < 4; ++r)
              if (kb + r > q_rel) sv[nt][r] = NEG_INF;
          }
        }

#pragma unroll
        for (int nt = 0; nt < 4; ++nt) {
#pragma unroll
          for (int r = 0; r < 4; ++r) sv[nt][r] = exp2f(sv[nt][r]);
          lsv += sv[nt];
        }
        bf16x8 apf[2];
#pragma unroll
        for (int a = 0; a < 2; ++a) {
          bf16x4 c0 = __builtin_convertvector(sv[2 * a], bf16x4);
          bf16x4 c1 = __builtin_convertvector(sv[2 * a + 1], bf16x4);
#pragma unroll
          for (int i = 0; i < 4; ++i) {
            apf[a][i] = c0[i];
            apf[a][4 + i] = c1[i];
          }
        }

#pragma unroll
        for (int nt = 0; nt < 4; ++nt) {
          const int R = nt * 16 + l16;
#pragma unroll
          for (int a = 0; a < 2; ++a) {
            bf16x8 bvf = *(const bf16x8*)&SMEM[vo + R * 64 +
                                               (((a * 4 + quad) ^ (l16 & 7)) *
                                                8)];
            Oacc[nt] = MFMA16(apf[a], bvf, Oacc[nt]);
          }
        }
      }
    }

    __syncthreads();
  }

  float ls_acc = lsv[0] + lsv[1] + lsv[2] + lsv[3];
  ls_acc += __shfl_xor(ls_acc, 16, 64);
  ls_acc += __shfl_xor(ls_acc, 32, 64);
  float rl[4];
#pragma unroll
  for (int r = 0; r < 4; ++r) rl[r] = 1.f / __shfl(ls_acc, quad * 4 + r, 64);
#pragma unroll
  for (int nt = 0; nt < 4; ++nt)
#pragma unroll
    for (int r = 0; r < 4; ++r) {
      int row = qt * 128 + wave * 16 + quad * 4 + r;
      Ob[(size_t)row * 1024 + nt * 16 + l16] = (bf16)(Oacc[nt][r] * rl[r]);
    }
}

// ---------------------------------------------------------------------------
// Launch
// ---------------------------------------------------------------------------
extern "C" void kernel_launch(void* const* d_in, const int* in_sizes, int n_in,
                              void* d_out, int out_size, void* d_ws,
                              size_t ws_size, hipStream_t stream) {
  (void)in_sizes; (void)n_in; (void)out_size; (void)ws_size;
  const float* x  = (const float*)d_in[0];
  const float* Wq = (const float*)d_in[1];
  const float* Wk = (const float*)d_in[2];
  const float* Wv = (const float*)d_in[3];
  const float* Wo = (const float*)d_in[4];
  float* out = (float*)d_out;

  bf16* ws = (bf16*)d_ws;
  const size_t WELEM = 1024u * 1024u;
  const size_t TELEM = 4096u * 1024u;
  bf16* wt  = ws;               // 4 transposed weights (8 MB)
  bf16* xbf = ws + 4 * WELEM;   // x bf16 (8 MB)
  bf16* q   = xbf + TELEM;      // q (z=0), k (z=1) via cStrideZ
  bf16* k   = q + TELEM;
  bf16* vt  = k + TELEM;        // V pre-transposed + pi-permuted by QKV
  bf16* ao  = vt + TELEM;

  const float QSCALE = 0.125f * 1.44269504088896340736f;  // 1/sqrt(64)*log2e

  prep<<<dim3(16, 16, 6), 256, 0, stream>>>(Wq, Wk, Wv, Wo, x, wt, xbf, out);
  gemm_bt<bf16, 4><<<dim3(256, 3), 256, 0, stream>>>(
      xbf, wt, q, (int)WELEM, (int)TELEM, QSCALE, vt);
  attn_fwd<<<dim3(512), 512, 0, stream>>>(q, k, vt, ao);
  gemm_proj_sk<<<dim3(1024), 256, 0, stream>>>(ao, wt + 3 * WELEM, out);
}

// Round 18
// 168.613 us; speedup vs baseline: 1.1121x; 1.1121x over previous
//
#include <hip/hip_runtime.h>
#include <hip/hip_bf16.h>

typedef __bf16 bf16;
typedef __bf16 bf16x4 __attribute__((ext_vector_type(4)));
typedef __bf16 bf16x8 __attribute__((ext_vector_type(8)));
typedef float f32x4 __attribute__((ext_vector_type(4)));

#define MFMA16(a, b, c) __builtin_amdgcn_mfma_f32_16x16x32_bf16((a), (b), (c), 0, 0, 0)

// async global->LDS, 16B per lane; LDS dest = wave-uniform base + lane*16.
__device__ __forceinline__ void async16(const void* g, void* l) {
  typedef const unsigned int __attribute__((address_space(1))) * GP;
  typedef unsigned int __attribute__((address_space(3))) * LP;
  __builtin_amdgcn_global_load_lds((GP)g, (LP)l, 16, 0, 0);
}

// ---------------------------------------------------------------------------
// prep: z<4 -> transpose+convert weight z (fp32 [1024x1024] -> bf16 Wt[n][k]);
// z==4 -> convert x fp32 -> bf16. grid (16,16,5) x 256 threads.
// ---------------------------------------------------------------------------
__global__ __launch_bounds__(256) void prep(
    const float* __restrict__ w0, const float* __restrict__ w1,
    const float* __restrict__ w2, const float* __restrict__ w3,
    const float* __restrict__ x, bf16* __restrict__ wtOut,
    bf16* __restrict__ xOut) {
  const int t = threadIdx.x;
  if (blockIdx.z == 4) {  // x conversion
    size_t base = ((size_t)(blockIdx.y * 16 + blockIdx.x)) * 16384;
#pragma unroll
    for (int p = 0; p < 16; ++p) {
      size_t i = base + (size_t)(p * 256 + t) * 4;
      f32x4 v = *(const f32x4*)&x[i];
      bf16 o[4];
#pragma unroll
      for (int j = 0; j < 4; ++j) o[j] = (bf16)v[j];
      *(ulong1*)&xOut[i] = *(ulong1*)o;
    }
    return;
  }
  __shared__ __align__(16) float tile[64][68];
  const float* src = (blockIdx.z == 0) ? w0 : (blockIdx.z == 1) ? w1
                   : (blockIdx.z == 2) ? w2 : w3;
  bf16* dst = wtOut + (size_t)blockIdx.z * (1024u * 1024u);
  const int bx = blockIdx.x, by = blockIdx.y;
#pragma unroll
  for (int p = 0; p < 4; ++p) {
    int idx = t + p * 256;
    int r = idx >> 4, c4 = idx & 15;
    *(f32x4*)&tile[r][c4 * 4] =
        *(const f32x4*)&src[(size_t)(by * 64 + r) * 1024 + bx * 64 + c4 * 4];
  }
  __syncthreads();
#pragma unroll
  for (int p = 0; p < 2; ++p) {
    int idx = t + p * 256;
    int rn = idx >> 3, c8 = idx & 7;
    bf16x8 v;
#pragma unroll
    for (int i = 0; i < 8; ++i) v[i] = (bf16)tile[c8 * 8 + i][rn];
    *(bf16x8*)&dst[(size_t)(bx * 64 + rn) * 1024 + by * 64 + c8 * 8] = v;
  }
}

// ---------------------------------------------------------------------------
// GEMM (round-13): C = A @ W (Bt[n][k]). 128 x (NI*32) tile, BK=32 dbuf
// global_load_lds, one barrier per K-step. XCD-swizzled 1D grid:
// bid = (y&7) + 8*(x + XT*(y>>3)); z in grid.y.
// z==0 scaled by scaleZ0; z==2 with vtOut: fused V^T epilogue with the
// PI-PERMUTED key layout (key s=16h+4q+r stored at col 8q+4h+r within each
// 32-block) so attention's PV B-frag is ONE contiguous b128.
// QKV: NI=4 (grid 256/z, 4 blk/CU via z-interleave). proj: NI=2 (grid 512,
// 2 blk/CU) — NI=4 at grid 256 is 1 blk/CU and measured SLOWER (r10, r16).
// ---------------------------------------------------------------------------
template <typename OutT, int NI>
__global__ __launch_bounds__(256, 4) void gemm_bt(
    const bf16* __restrict__ A, const bf16* __restrict__ Bt,
    OutT* __restrict__ C, int btStrideZ, int cStrideZ, float scaleZ0,
    bf16* __restrict__ vtOut) {
  constexpr int XT = 1024 / (NI * 32);
  const int bid = blockIdx.x;
  const int rr = bid & 7, tt = bid >> 3;
  const int xb = tt % XT, yb = (tt / XT) * 8 + rr;
  const int zi = blockIdx.y;

  const int tid = threadIdx.x;
  const int wave = tid >> 6, lane = tid & 63;
  const int quad = lane >> 4, l16 = lane & 15;
  const int wm = wave >> 1, wn = wave & 1;
  const int m0 = yb * 128, n0 = xb * (NI * 32);
  const bf16* Bz = Bt + (size_t)zi * (size_t)btStrideZ;
  OutT* Cz = C + (size_t)zi * (size_t)cStrideZ;
  const float sc = (zi == 0) ? scaleZ0 : 1.0f;

  __shared__ __align__(16) bf16 lsA[2][128 * 32];
  __shared__ __align__(16) bf16 lsB[2][NI * 32 * 32];

  const int lrow = lane >> 2;
  const int cgX = (lane & 3) ^ ((lrow >> 1) & 3);
  const int fR = (l16 >> 1) & 3;

  f32x4 acc[4][NI];
#pragma unroll
  for (int i = 0; i < 4; ++i)
#pragma unroll
    for (int j = 0; j < NI; ++j) acc[i][j] = (f32x4){0.f, 0.f, 0.f, 0.f};

#pragma unroll
  for (int c = 0; c < 2; ++c) {
    int chunk = wave * 2 + c;
    int row = chunk * 16 + lrow;
    async16(&A[(size_t)(m0 + row) * 1024 + cgX * 8], &lsA[0][chunk * 512]);
  }
#pragma unroll
  for (int c = 0; c < NI / 2; ++c) {
    int chunk = wave * (NI / 2) + c;
    int row = chunk * 16 + lrow;
    async16(&Bz[(size_t)(n0 + row) * 1024 + cgX * 8], &lsB[0][chunk * 512]);
  }
  __syncthreads();

  for (int it = 0; it < 32; ++it) {
    const int cur = it & 1;
    if (it < 31) {
      int k0n = (it + 1) * 32;
#pragma unroll
      for (int c = 0; c < 2; ++c) {
        int chunk = wave * 2 + c;
        int row = chunk * 16 + lrow;
        async16(&A[(size_t)(m0 + row) * 1024 + k0n + cgX * 8],
                &lsA[cur ^ 1][chunk * 512]);
      }
#pragma unroll
      for (int c = 0; c < NI / 2; ++c) {
        int chunk = wave * (NI / 2) + c;
        int row = chunk * 16 + lrow;
        async16(&Bz[(size_t)(n0 + row) * 1024 + k0n + cgX * 8],
                &lsB[cur ^ 1][chunk * 512]);
      }
    }

    bf16x8 af[4], bfr[NI];
#pragma unroll
    for (int i = 0; i < 4; ++i) {
      int ra = wm * 64 + i * 16 + l16;
      af[i] = *(const bf16x8*)&lsA[cur][ra * 32 + ((quad ^ fR) * 8)];
    }
#pragma unroll
    for (int ni = 0; ni < NI; ++ni) {
      int rb = wn * (NI * 16) + ni * 16 + l16;
      bfr[ni] = *(const bf16x8*)&lsB[cur][rb * 32 + ((quad ^ fR) * 8)];
    }
#pragma unroll
    for (int mi = 0; mi < 4; ++mi)
#pragma unroll
      for (int ni = 0; ni < NI; ++ni)
        acc[mi][ni] = MFMA16(af[mi], bfr[ni], acc[mi][ni]);

    __syncthreads();
  }

  if (zi == 2 && vtOut != nullptr) {
    // V: transposed per head -> vt[(b*16+h)][d][sPerm], pi-permuted keys.
#pragma unroll
    for (int mi = 0; mi < 4; ++mi)
#pragma unroll
      for (int ni = 0; ni < NI; ++ni) {
        int col = n0 + wn * (NI * 16) + ni * 16 + l16;
        int hd = col >> 6, d = col & 63;
        int row = m0 + wm * 64 + mi * 16 + quad * 4;
        int b = row >> 11, s = row & 2047;
        int s32 = s & 31;
        int sp = (s & ~31) + ((s32 & 12) << 1) + ((s32 >> 4) << 2);
        bf16 o[4];
#pragma unroll
        for (int r = 0; r < 4; ++r) o[r] = (bf16)acc[mi][ni][r];
        *(ulong1*)&vtOut[((size_t)(b * 16 + hd) * 64 + d) * 2048 + sp] =
            *(ulong1*)o;
      }
  } else {
#pragma unroll
    for (int mi = 0; mi < 4; ++mi)
#pragma unroll
      for (int ni = 0; ni < NI; ++ni) {
        int col = n0 + wn * (NI * 16) + ni * 16 + l16;
#pragma unroll
        for (int r = 0; r < 4; ++r) {
          int row = m0 + wm * 64 + mi * 16 + quad * 4 + r;
          Cz[(size_t)row * 1024 + col] = (OutT)(acc[mi][ni][r] * sc);
        }
      }
  }
}

// ---------------------------------------------------------------------------
// Flash attention v7 (round-16, measured ~38 us): register-resident P +
// 4-slot LDS rotation, one barrier per PAIR of 64-key tiles (halved barrier
// count, prefetch->drain distance ~a full pair of compute). LDS 64KB
// (4 x 8192-elem K/V slots; Q staging overlays slot 2). 512 thr, 128-row
// q-tile, 8 waves x 16 q-rows; pi-permuted V -> PV B-frag is one b128.
// Q pre-scaled by 0.125*log2e in the QKV GEMM -> p = exp2(s), fixed-max
// softmax (scores bounded, no overflow).
// ---------------------------------------------------------------------------
__global__ __launch_bounds__(512, 4) void attn_fwd(
    const bf16* __restrict__ Q, const bf16* __restrict__ K,
    const bf16* __restrict__ Vt, bf16* __restrict__ O) {
  const int bid = blockIdx.x;
  const int x = bid & 15, hb = bid >> 4;
  const int h = hb & 15, b = hb >> 4;
  const int qt = b ? (15 - x) : x;
  const int tid = threadIdx.x;
  const int wave = tid >> 6, lane = tid & 63;
  const int quad = lane >> 4, l16 = lane & 15;

  __shared__ __align__(16) bf16 SMEM[32768];  // 64 KB, 4 slots x 8192
  bf16* Qs = &SMEM[16384];  // Q overlays slot 2

  const size_t base = ((size_t)b * 2048) * 1024 + (size_t)h * 64;
  const bf16* Qb = Q + base;
  const bf16* Kb = K + base;
  const bf16* Vtb = Vt + ((size_t)(b * 16 + h)) * 64 * 2048;
  bf16* Ob = O + base;

  const int lrow = lane >> 3;
  const int cgX = (lane & 7) ^ lrow;

#pragma unroll
  for (int c = 0; c < 2; ++c) {
    int chunk = wave * 2 + c;
    int row = chunk * 8 + lrow;
    async16(&Qb[(size_t)(qt * 128 + row) * 1024 + cgX * 8], &Qs[chunk * 512]);
  }
  {
    int row = wave * 8 + lrow;
    async16(&Kb[(size_t)row * 1024 + cgX * 8], &SMEM[0 * 8192 + wave * 512]);
    async16(&Vtb[(size_t)row * 2048 + cgX * 8],
            &SMEM[0 * 8192 + 4096 + wave * 512]);
    async16(&Kb[(size_t)(64 + row) * 1024 + cgX * 8],
            &SMEM[1 * 8192 + wave * 512]);
    async16(&Vtb[(size_t)row * 2048 + 64 + cgX * 8],
            &SMEM[1 * 8192 + 4096 + wave * 512]);
  }
  __syncthreads();

  bf16x8 aq[2];
#pragma unroll
  for (int ks = 0; ks < 2; ++ks) {
    int row = wave * 16 + l16;
    aq[ks] = *(const bf16x8*)&Qs[row * 64 + (((ks * 4 + quad) ^ (l16 & 7)) * 8)];
  }
  __syncthreads();  // Q-frag reads done before slot 2 is overwritten

  const float NEG_INF = -__builtin_inff();
  f32x4 lsv = (f32x4){0.f, 0.f, 0.f, 0.f};
  f32x4 Oacc[4];
#pragma unroll
  for (int nt = 0; nt < 4; ++nt) Oacc[nt] = (f32x4){0.f, 0.f, 0.f, 0.f};

  const int kt_end = 2 * qt + 1;           // tile count 2qt+2 (even)
  const int ktd = 2 * qt + (wave >> 2);    // this wave's diagonal tile

  for (int ktp = 0; ktp <= kt_end; ktp += 2) {
    {
      int row = wave * 8 + lrow;
      if (ktp + 2 <= kt_end) {
        int s2 = (ktp + 2) & 3;
        async16(&Kb[(size_t)((ktp + 2) * 64 + row) * 1024 + cgX * 8],
                &SMEM[s2 * 8192 + wave * 512]);
        async16(&Vtb[(size_t)row * 2048 + (ktp + 2) * 64 + cgX * 8],
                &SMEM[s2 * 8192 + 4096 + wave * 512]);
      }
      if (ktp + 3 <= kt_end) {
        int s3 = (ktp + 3) & 3;
        async16(&Kb[(size_t)((ktp + 3) * 64 + row) * 1024 + cgX * 8],
                &SMEM[s3 * 8192 + wave * 512]);
        async16(&Vtb[(size_t)row * 2048 + (ktp + 3) * 64 + cgX * 8],
                &SMEM[s3 * 8192 + 4096 + wave * 512]);
      }
    }

#pragma unroll
    for (int sub = 0; sub < 2; ++sub) {
      const int kt = ktp + sub;
      const int ko = (kt & 3) * 8192;
      const int vo = ko + 4096;
      if (kt <= ktd) {
        f32x4 sv[4];
#pragma unroll
        for (int nt = 0; nt < 4; ++nt) {
          int row = nt * 16 + l16;
          bf16x8 bk0 = *(const bf16x8*)&SMEM[ko + row * 64 +
                                             ((quad ^ (l16 & 7)) * 8)];
          bf16x8 bk1 = *(const bf16x8*)&SMEM[ko + row * 64 +
                                             (((4 + quad) ^ (l16 & 7)) * 8)];
          sv[nt] = (f32x4){0.f, 0.f, 0.f, 0.f};
          sv[nt] = MFMA16(bk0, aq[0], sv[nt]);
          sv[nt] = MFMA16(bk1, aq[1], sv[nt]);
        }

        if (kt == ktd) {
          const int q_rel = wave * 16 + l16;
          const int cb = (kt - 2 * qt) * 64;
#pragma unroll
          for (int nt = 0; nt < 4; ++nt) {
            const int kb = cb + nt * 16 + quad * 4;
#pragma unroll
            for (int r = 0; r < 4; ++r)
              if (kb + r > q_rel) sv[nt][r] = NEG_INF;
          }
        }

#pragma unroll
        for (int nt = 0; nt < 4; ++nt) {
#pragma unroll
          for (int r = 0; r < 4; ++r) sv[nt][r] = exp2f(sv[nt][r]);
          lsv += sv[nt];
        }
        bf16x8 apf[2];
#pragma unroll
        for (int a = 0; a < 2; ++a) {
          bf16x4 c0 = __builtin_convertvector(sv[2 * a], bf16x4);
          bf16x4 c1 = __builtin_convertvector(sv[2 * a + 1], bf16x4);
#pragma unroll
          for (int i = 0; i < 4; ++i) {
            apf[a][i] = c0[i];
            apf[a][4 + i] = c1[i];
          }
        }

#pragma unroll
        for (int nt = 0; nt < 4; ++nt) {
          const int R = nt * 16 + l16;
#pragma unroll
          for (int a = 0; a < 2; ++a) {
            bf16x8 bvf = *(const bf16x8*)&SMEM[vo + R * 64 +
                                               (((a * 4 + quad) ^ (l16 & 7)) *
                                                8)];
            Oacc[nt] = MFMA16(apf[a], bvf, Oacc[nt]);
          }
        }
      }
    }

    __syncthreads();
  }

  float ls_acc = lsv[0] + lsv[1] + lsv[2] + lsv[3];
  ls_acc += __shfl_xor(ls_acc, 16, 64);
  ls_acc += __shfl_xor(ls_acc, 32, 64);
  float rl[4];
#pragma unroll
  for (int r = 0; r < 4; ++r) rl[r] = 1.f / __shfl(ls_acc, quad * 4 + r, 64);
#pragma unroll
  for (int nt = 0; nt < 4; ++nt)
#pragma unroll
    for (int r = 0; r < 4; ++r) {
      int row = qt * 128 + wave * 16 + quad * 4 + r;
      Ob[(size_t)row * 1024 + nt * 16 + l16] = (bf16)(Oacc[nt][r] * rl[r]);
    }
}

// ---------------------------------------------------------------------------
// Launch
// ---------------------------------------------------------------------------
extern "C" void kernel_launch(void* const* d_in, const int* in_sizes, int n_in,
                              void* d_out, int out_size, void* d_ws,
                              size_t ws_size, hipStream_t stream) {
  (void)in_sizes; (void)n_in; (void)out_size; (void)ws_size;
  const float* x  = (const float*)d_in[0];
  const float* Wq = (const float*)d_in[1];
  const float* Wk = (const float*)d_in[2];
  const float* Wv = (const float*)d_in[3];
  const float* Wo = (const float*)d_in[4];
  float* out = (float*)d_out;

  bf16* ws = (bf16*)d_ws;
  const size_t WELEM = 1024u * 1024u;
  const size_t TELEM = 4096u * 1024u;
  bf16* wt  = ws;               // 4 transposed weights (8 MB)
  bf16* xbf = ws + 4 * WELEM;   // x bf16 (8 MB)
  bf16* q   = xbf + TELEM;      // q (z=0), k (z=1) via cStrideZ
  bf16* k   = q + TELEM;
  bf16* vt  = k + TELEM;        // V pre-transposed + pi-permuted by QKV
  bf16* ao  = vt + TELEM;

  const float QSCALE = 0.125f * 1.44269504088896340736f;  // 1/sqrt(64)*log2e

  prep<<<dim3(16, 16, 5), 256, 0, stream>>>(Wq, Wk, Wv, Wo, x, wt, xbf);
  gemm_bt<bf16, 4><<<dim3(256, 3), 256, 0, stream>>>(
      xbf, wt, q, (int)WELEM, (int)TELEM, QSCALE, vt);
  attn_fwd<<<dim3(512), 512, 0, stream>>>(q, k, vt, ao);
  gemm_bt<float, 2><<<dim3(512, 1), 256, 0, stream>>>(
      ao, wt + 3 * WELEM, out, 0, 0, 1.0f, nullptr);
}